// Round 1
// baseline (233.128 us; speedup 1.0000x reference)
//
#include <hip/hip_runtime.h>
#include <math.h>

#define NT      32768
#define DIM     2048
#define NE      64
#define RSCALE  2.5f
#define REPS    1e-20f

// 512 blocks x 256 threads; 64 tokens per block.
// Thread tile: 4 tokens x 4 experts. col = tid&15 (expert quad), row = tid>>4 (token quad).
__global__ __launch_bounds__(256) void router_kernel(
    const float* __restrict__ H,
    const float* __restrict__ W,
    const float* __restrict__ B,
    float* __restrict__ out)
{
    __shared__ __align__(16) float Hs[64][64];   // tokens x K-chunk, float4-swizzled
    __shared__ __align__(16) float Ws[64][64];   // experts x K-chunk, float4-swizzled
    __shared__ float Sc[64][65];                 // sigmoid scores, +1 pad
    __shared__ float Bs[64];

    const int tid = threadIdx.x;
    const int col = tid & 15;
    const int row = tid >> 4;
    const size_t tb = (size_t)blockIdx.x * 64;

    if (tid < 64) Bs[tid] = B[tid];

    double acc[4][4];
    #pragma unroll
    for (int t = 0; t < 4; ++t)
        #pragma unroll
        for (int j = 0; j < 4; ++j) acc[t][j] = 0.0;

    const int st = tid >> 4;   // staging row 0..15
    const int sk = tid & 15;   // staging float4 column 0..15

    for (int k0 = 0; k0 < DIM; k0 += 64) {
        __syncthreads();
        // stage H tile (64 tokens x 64 dims) and W tile (64 experts x 64 dims)
        #pragma unroll
        for (int it = 0; it < 4; ++it) {
            const int r = st + it * 16;           // token / expert row 0..63
            const int sl = sk ^ ((r >> 2) & 7);   // XOR swizzle (bank-conflict-free reads)
            float4 hv = *(const float4*)&H[(tb + (size_t)r) * DIM + k0 + sk * 4];
            ((float4*)&Hs[r][0])[sl] = hv;
            float4 wv = *(const float4*)&W[(size_t)r * DIM + k0 + sk * 4];
            ((float4*)&Ws[r][0])[sl] = wv;
        }
        __syncthreads();

        float c[4][4];
        #pragma unroll
        for (int t = 0; t < 4; ++t)
            #pragma unroll
            for (int j = 0; j < 4; ++j) c[t][j] = 0.0f;

        #pragma unroll 4
        for (int kk = 0; kk < 16; ++kk) {
            float4 h4[4], w4[4];
            #pragma unroll
            for (int t = 0; t < 4; ++t)
                h4[t] = ((const float4*)&Hs[row * 4 + t][0])[kk ^ (row & 7)];
            #pragma unroll
            for (int j = 0; j < 4; ++j)
                w4[j] = ((const float4*)&Ws[col * 4 + j][0])[kk ^ (col & 7)];
            #pragma unroll
            for (int t = 0; t < 4; ++t)
                #pragma unroll
                for (int j = 0; j < 4; ++j) {
                    float s = c[t][j];
                    s = fmaf(h4[t].x, w4[j].x, s);
                    s = fmaf(h4[t].y, w4[j].y, s);
                    s = fmaf(h4[t].z, w4[j].z, s);
                    s = fmaf(h4[t].w, w4[j].w, s);
                    c[t][j] = s;
                }
            // flush 16-dim subchunk into fp64 master accumulator (precision for rank stability)
            if ((kk & 3) == 3) {
                #pragma unroll
                for (int t = 0; t < 4; ++t)
                    #pragma unroll
                    for (int j = 0; j < 4; ++j) {
                        acc[t][j] += (double)c[t][j];
                        c[t][j] = 0.0f;
                    }
            }
        }
    }

    // sigmoid scores into LDS
    #pragma unroll
    for (int t = 0; t < 4; ++t)
        #pragma unroll
        for (int j = 0; j < 4; ++j) {
            float logit = (float)acc[t][j];
            float s = 1.0f / (1.0f + expf(-logit));
            Sc[row * 4 + t][col * 4 + j] = s;
        }
    __syncthreads();

    // one thread per token: grouped top-k (strict > scans == jax.lax.top_k stable order)
    if (tid < 64) {
        const float* sc = Sc[tid];
        float gs[8];
        #pragma unroll
        for (int g = 0; g < 8; ++g) {
            float m1 = -1e30f, m2 = -1e30f;
            #pragma unroll
            for (int j = 0; j < 8; ++j) {
                float v = sc[g * 8 + j] + Bs[g * 8 + j];
                if (v > m1) { m2 = m1; m1 = v; }
                else if (v > m2) { m2 = v; }
            }
            gs[g] = m1 + m2;
        }
        unsigned gmask = 0;
        for (int i = 0; i < 4; ++i) {
            float best = -1e30f; int bg = 0;
            for (int g = 0; g < 8; ++g)
                if (!((gmask >> g) & 1u) && gs[g] > best) { best = gs[g]; bg = g; }
            gmask |= 1u << bg;
        }
        unsigned long long picked = 0ull;
        int   idxs[8];
        float wts[8];
        float wsum = 0.0f;
        for (int i = 0; i < 8; ++i) {
            float best = -1e30f; int bi = 0;
            for (int e = 0; e < 64; ++e) {
                if ((picked >> e) & 1ull) continue;
                float v = ((gmask >> (e >> 3)) & 1u) ? (sc[e] + Bs[e]) : 0.0f;
                if (v > best) { best = v; bi = e; }
            }
            picked |= 1ull << bi;
            idxs[i] = bi;
            wts[i] = sc[bi];
            wsum += sc[bi];
        }
        const float scale = RSCALE / (wsum + REPS);
        const size_t token = tb + tid;
        #pragma unroll
        for (int i = 0; i < 8; ++i) {
            out[token * 8 + i] = (float)idxs[i];
            out[(size_t)NT * 8 + token * 8 + i] = wts[i] * scale;
        }
    }
}

extern "C" void kernel_launch(void* const* d_in, const int* in_sizes, int n_in,
                              void* d_out, int out_size, void* d_ws, size_t ws_size,
                              hipStream_t stream) {
    (void)in_sizes; (void)n_in; (void)out_size; (void)d_ws; (void)ws_size;
    const float* H = (const float*)d_in[0];
    const float* W = (const float*)d_in[1];
    const float* B = (const float*)d_in[2];
    float* out = (float*)d_out;
    router_kernel<<<dim3(NT / 64), dim3(256), 0, stream>>>(H, W, B, out);
}